// Round 10
// baseline (533.803 us; speedup 1.0000x reference)
//
#include <hip/hip_runtime.h>
#include <hip/hip_bf16.h>
#include <math.h>

// COSGATEncoder: N=50000, E=1280000, D=64, HEADS=1. f32 in/out (runtime-detected,
// bf16 fallback), edge_index int64 (runtime-detected, int32 fallback).
// R10: phase-3 p/src via wave-private LDS (kills shfl->gather serial chain),
// (src,gate) stashed in LDS during phase 1 (no global csr re-read), unroll 8
// both gather loops; k_count folded into k_init.

constexpr int D = 64;
constexpr int CAP = 256;  // LDS-resident edges per node; overflow -> global bufs
constexpr float NEG_SLOPE = 0.2f;
constexpr float EPS_COS = 1e-8f;
constexpr float EPS_SM = 1e-16f;

typedef _Float16 half2_t __attribute__((ext_vector_type(2)));
union U16x8 {
  uint4 u;
  half2_t h[4];
};

__device__ __forceinline__ float wred_sum(float v) {
#pragma unroll
  for (int off = 32; off > 0; off >>= 1) v += __shfl_xor(v, off, 64);
  return v;
}
__device__ __forceinline__ float elu1(float x) { return x > 0.f ? x : __expf(x) - 1.f; }
__device__ __forceinline__ float sane(float v) {
  return (v == v && fabsf(v) < 1e30f) ? v : 0.f;
}
__device__ __forceinline__ float ldv(const void* p, size_t i, int f32) {
  return f32 ? ((const float*)p)[i]
             : __bfloat162float(((const __hip_bfloat16*)p)[i]);
}
__device__ __forceinline__ void stv(void* p, size_t i, int f32, float v) {
  if (f32) ((float*)p)[i] = v;
  else ((__hip_bfloat16*)p)[i] = __float2bfloat16(v);
}
__device__ __forceinline__ float b2f(unsigned short u) {
  return __uint_as_float(((unsigned int)u) << 16);
}
__device__ __forceinline__ void unp8(uint4 u, float* f) {
  f[0] = __uint_as_float(u.x << 16);
  f[1] = __uint_as_float(u.x & 0xffff0000u);
  f[2] = __uint_as_float(u.y << 16);
  f[3] = __uint_as_float(u.y & 0xffff0000u);
  f[4] = __uint_as_float(u.z << 16);
  f[5] = __uint_as_float(u.z & 0xffff0000u);
  f[6] = __uint_as_float(u.w << 16);
  f[7] = __uint_as_float(u.w & 0xffff0000u);
}
__device__ __forceinline__ float dot8(const U16x8& a, const U16x8& b) {
  float d = 0.f;
#if __has_builtin(__builtin_amdgcn_fdot2)
#pragma unroll
  for (int i = 0; i < 4; ++i) d = __builtin_amdgcn_fdot2(a.h[i], b.h[i], d, false);
#else
#pragma unroll
  for (int i = 0; i < 4; ++i) {
    d += (float)a.h[i][0] * (float)b.h[i][0];
    d += (float)a.h[i][1] * (float)b.h[i][1];
  }
#endif
  return d;
}

// shared prep body: node features (lane=feature) -> fhat(f16), Hmat(bf16), a_l, a_r
__device__ __forceinline__ void prep_node(float f, int f32, int wid, int lane,
                                          const void* __restrict__ W,
                                          const void* __restrict__ att,
                                          _Float16* __restrict__ fhat,
                                          __hip_bfloat16* __restrict__ Hmat,
                                          float* __restrict__ a_l,
                                          float* __restrict__ a_r) {
  float n2 = wred_sum(f * f);
  float nrm = fmaxf(sqrtf(n2), EPS_COS);
  fhat[(size_t)wid * D + lane] = (_Float16)(f / nrm);
  float Hc = 0.f;
  if (f32) {
    const float* Wf = (const float*)W;
#pragma unroll 8
    for (int k = 0; k < D; ++k) Hc += __shfl(f, k, 64) * Wf[k * D + lane];
  } else {
    const __hip_bfloat16* Wb = (const __hip_bfloat16*)W;
#pragma unroll 8
    for (int k = 0; k < D; ++k) Hc += __shfl(f, k, 64) * __bfloat162float(Wb[k * D + lane]);
  }
  Hmat[(size_t)wid * D + lane] = __float2bfloat16(Hc);
  float al = wred_sum(Hc * ldv(att, lane, f32));
  float ar = wred_sum(Hc * ldv(att, D + lane, f32));
  if (lane == 0) {
    a_l[wid] = al;
    a_r[wid] = ar;
  }
}

// fused: per-block dtype detect + degree count + layer-0 prep
// (counts zeroed by hipMemsetAsync before this kernel)
__global__ void __launch_bounds__(256) k_init(const unsigned short* __restrict__ xu,
                                              const int* __restrict__ ei,
                                              int* __restrict__ flags,
                                              int* __restrict__ counts,
                                              const void* __restrict__ x,
                                              const void* __restrict__ W,
                                              const void* __restrict__ att,
                                              _Float16* __restrict__ fhat,
                                              __hip_bfloat16* __restrict__ Hmat,
                                              float* __restrict__ a_l,
                                              float* __restrict__ a_r, int N, int E) {
  __shared__ int sf[2];
  const int tid = threadIdx.x;
  if (tid < 64) {
    float v = b2f(xu[tid]);
    float a = fabsf(v);
    unsigned long long m = __ballot(a > 1e-4f && a < 100.f);
    unsigned long long m2 = __ballot(ei[2 * tid + 1] != 0);
    if (tid == 0) {
      sf[0] = (__popcll(m) >= 60) ? 0 : 1;  // 1 => f32
      sf[1] = (m2 == 0ull) ? 1 : 0;         // 1 => int64
      if (blockIdx.x == 0) {
        flags[0] = sf[0];
        flags[1] = sf[1];
      }
    }
  }
  __syncthreads();
  const int f32 = sf[0], wide = sf[1];
  // degree count: 2 edges per thread
  {
    const int e0 = (blockIdx.x * 256 + tid) * 2;
    if (e0 < E) {
      int d0, d1;
      const bool has1 = (e0 + 1 < E);
      if (wide) {
        int4 v = *(const int4*)(ei + 2 * (size_t)E + 2 * (size_t)e0);
        d0 = v.x;
        d1 = v.z;
      } else {
        int2 v = *(const int2*)(ei + (size_t)E + e0);
        d0 = v.x;
        d1 = v.y;
      }
      atomicAdd(&counts[min(max(d0, 0), N - 1)], 1);
      if (has1) atomicAdd(&counts[min(max(d1, 0), N - 1)], 1);
    }
  }
  const int lane = tid & 63;
  const int wid = blockIdx.x * 4 + (tid >> 6);
  if (wid >= N) return;
  float f = ldv(x, (size_t)wid * D + lane, f32);
  prep_node(f, f32, wid, lane, W, att, fhat, Hmat, a_l, a_r);
}

// 3-pass multiblock exclusive scan
__global__ void k_scanA(const int* __restrict__ counts, int* __restrict__ row_ptr,
                        int* __restrict__ partials, int n) {
  __shared__ int sm[256];
  const int t = threadIdx.x;
  const int i = blockIdx.x * 256 + t;
  int v = (i < n) ? counts[i] : 0;
  sm[t] = v;
  __syncthreads();
  for (int off = 1; off < 256; off <<= 1) {
    int u = (t >= off) ? sm[t - off] : 0;
    __syncthreads();
    sm[t] += u;
    __syncthreads();
  }
  if (i < n) row_ptr[i] = sm[t] - v;
  if (t == 255) partials[blockIdx.x] = sm[255];
}
__global__ void __launch_bounds__(1024) k_scanB(int* __restrict__ partials,
                                                int* __restrict__ row_ptr,
                                                int nb, int n) {
  __shared__ int sm[1024];
  const int t = threadIdx.x;
  int v = (t < nb) ? partials[t] : 0;
  sm[t] = v;
  __syncthreads();
  for (int off = 1; off < 1024; off <<= 1) {
    int u = (t >= off) ? sm[t - off] : 0;
    __syncthreads();
    sm[t] += u;
    __syncthreads();
  }
  if (t < nb) partials[t] = sm[t] - v;
  if (t == nb - 1) row_ptr[n] = sm[t];
}
__global__ void k_scanC(int* __restrict__ row_ptr, int* __restrict__ wptr,
                        const int* __restrict__ partials, int n) {
  const int i = blockIdx.x * 256 + threadIdx.x;
  if (i < n) {
    int r = row_ptr[i] + partials[blockIdx.x];
    row_ptr[i] = r;
    wptr[i] = r;
  }
}

// packed entry: .x = src, .y = gate bits (float)
__global__ void k_fill(const int* __restrict__ ei, const void* __restrict__ w,
                       int E, int N, const int* __restrict__ flags,
                       int* __restrict__ wptr, int2* __restrict__ csr) {
  int e0 = (blockIdx.x * blockDim.x + threadIdx.x) * 2;
  if (e0 >= E) return;
  const int wide = flags[1], f32 = flags[0];
  const bool has1 = (e0 + 1 < E);
  int s0, s1, d0, d1;
  if (wide) {
    int4 vs = *(const int4*)(ei + 2 * (size_t)e0);
    int4 vd = *(const int4*)(ei + 2 * (size_t)E + 2 * (size_t)e0);
    s0 = vs.x; s1 = vs.z; d0 = vd.x; d1 = vd.z;
  } else {
    int2 vs = *(const int2*)(ei + e0);
    int2 vd = *(const int2*)(ei + (size_t)E + e0);
    s0 = vs.x; s1 = vs.y; d0 = vd.x; d1 = vd.y;
  }
  float w0, w1 = 0.f;
  if (f32) {
    float2 wv = *(const float2*)((const float*)w + e0);
    w0 = wv.x; w1 = wv.y;
  } else {
    const __hip_bfloat16* wb = (const __hip_bfloat16*)w;
    w0 = __bfloat162float(wb[e0]);
    if (has1) w1 = __bfloat162float(wb[e0 + 1]);
  }
  float g0 = fminf(fmaxf(1.f - 0.25f * fminf(w0, 4.f), 0.f), 1.f);
  int p0 = atomicAdd(&wptr[min(max(d0, 0), N - 1)], 1);
  p0 = min(max(p0, 0), E - 1);
  csr[p0] = make_int2(min(max(s0, 0), N - 1), __float_as_int(g0));
  if (has1) {
    float g1 = fminf(fmaxf(1.f - 0.25f * fminf(w1, 4.f), 0.f), 1.f);
    int p1 = atomicAdd(&wptr[min(max(d1, 0), N - 1)], 1);
    p1 = min(max(p1, 0), E - 1);
    csr[p1] = make_int2(min(max(s1, 0), N - 1), __float_as_int(g1));
  }
}

// standalone prep (fallback path when ws too small for fused buffers)
__global__ void __launch_bounds__(256) k_prep(const void* __restrict__ xin,
                                              const void* __restrict__ W,
                                              const void* __restrict__ att,
                                              const int* __restrict__ flags,
                                              _Float16* __restrict__ fhat,
                                              __hip_bfloat16* __restrict__ Hmat,
                                              float* __restrict__ a_l,
                                              float* __restrict__ a_r, int N) {
  const int lane = threadIdx.x & 63;
  const int wid = (blockIdx.x * 256 + threadIdx.x) >> 6;
  if (wid >= N) return;
  const int f32 = flags[0];
  float f = ldv(xin, (size_t)wid * D + lane, f32);
  prep_node(f, f32, wid, lane, W, att, fhat, Hmat, a_l, a_r);
}

// ---------------- edge kernel: wave per dst node, 8-edge/8-lane groups ----------------
// mode 0: layer 0, fused prep of next layer; mode 1: layer 1, fused residual MLP;
// mode 2: layer 0 fallback (writes h to out)
__global__ void __launch_bounds__(256) k_edge(const int* __restrict__ row_ptr,
                                              const int2* __restrict__ csr,
                                              _Float16* __restrict__ lbuf,
                                              _Float16* __restrict__ cbuf,
                                              const _Float16* __restrict__ fhat,
                                              const __hip_bfloat16* __restrict__ Hmat,
                                              const float* __restrict__ a_l,
                                              const float* __restrict__ a_r,
                                              const void* __restrict__ beta,
                                              const void* __restrict__ bias,
                                              const void* __restrict__ x,
                                              const void* __restrict__ rW1,
                                              const void* __restrict__ rb1,
                                              const void* __restrict__ rW2,
                                              const void* __restrict__ rb2,
                                              const void* __restrict__ Wn,
                                              const void* __restrict__ attn,
                                              _Float16* __restrict__ fh2,
                                              __hip_bfloat16* __restrict__ Hm2,
                                              float* __restrict__ al2,
                                              float* __restrict__ ar2,
                                              const int* __restrict__ flags,
                                              void* __restrict__ out,
                                              int N, int E, int mode) {
  const int lane = threadIdx.x & 63;
  const int wv = threadIdx.x >> 6;
  const int wid = blockIdx.x * 4 + wv;
  __shared__ float2 lds_lc[4][CAP];  // (l, c)
  __shared__ float2 lds_sg[4][CAP];  // (src bits, gate) -> later (src bits, p)
  __shared__ float lds_t[4][D];
  if (wid >= N) return;
  const int f32 = flags[0];
  const int g = lane >> 3;   // edge slot in 8-edge group
  const int sub = lane & 7;  // feature block: [8*sub, 8*sub+8)
  const int s = min(max(row_ptr[wid], 0), E);
  const int e = min(max(row_ptr[wid + 1], s), E);
  const int deg = e - s;
  const float aln = a_l[wid];
  float2* lc = lds_lc[wv];
  float2* sg = lds_sg[wv];

  U16x8 fn;
  fn.u = ((const uint4*)(fhat + (size_t)wid * D))[sub];

  // ---- phase 1: 8 edges/iter (unroll 8), (l,c)->LDS, (src,gate)->LDS ----
  float m1 = -1e30f, m2 = -1e30f;
#pragma unroll 8
  for (int base = 0; base < deg; base += 8) {
    const int j = base + g;
    const bool val = j < deg;
    const int2 en = val ? csr[s + j] : make_int2(wid, 0);
    const int src = en.x;
    U16x8 hv;
    hv.u = ((const uint4*)(fhat + (size_t)src * D))[sub];
    float d = dot8(fn, hv);
    d += __shfl_xor(d, 1, 64);
    d += __shfl_xor(d, 2, 64);
    d += __shfl_xor(d, 4, 64);
    float l = aln + a_r[src];
    l = (l >= 0.f) ? l : NEG_SLOPE * l;
    if (val) {
      m1 = fmaxf(m1, l);
      m2 = fmaxf(m2, d);
      if (sub == 0) {
        if (j < CAP) {
          lc[j] = make_float2(l, d);
          sg[j] = make_float2(__int_as_float(en.x), __int_as_float(en.y));
        } else {
          lbuf[s + j] = (_Float16)l;
          cbuf[s + j] = (_Float16)d;
        }
      }
    }
  }
  m1 = fmaxf(m1, __shfl_xor(m1, 8, 64));
  m1 = fmaxf(m1, __shfl_xor(m1, 16, 64));
  m1 = fmaxf(m1, __shfl_xor(m1, 32, 64));
  m2 = fmaxf(m2, __shfl_xor(m2, 8, 64));
  m2 = fmaxf(m2, __shfl_xor(m2, 16, 64));
  m2 = fmaxf(m2, __shfl_xor(m2, 32, 64));

  // ---- merged phase 2 + 3-prep (LDS only for deg<=CAP) ----
  float el[4] = {0.f, 0.f, 0.f, 0.f}, ec[4] = {0.f, 0.f, 0.f, 0.f};
  float gg[4] = {0.f, 0.f, 0.f, 0.f};
  int q[4] = {0, 0, 0, 0};
  float ps1 = 0.f, ps2 = 0.f;
#pragma unroll
  for (int c = 0; c < 4; ++c) {
    const int j = c * 64 + lane;
    if (c * 64 < deg && j < deg) {
      float2 en = sg[j];
      q[c] = __float_as_int(en.x);
      gg[c] = __int_as_float(__float_as_int(en.y));
      float2 t = lc[j];
      el[c] = __expf(t.x - m1);
      ec[c] = __expf(t.y - m2);
      ps1 += el[c];
      ps2 += ec[c];
    }
  }
  for (int c = 4; c * 64 < deg; ++c) {
    const int j = c * 64 + lane;
    if (j < deg) {
      ps1 += __expf((float)lbuf[s + j] - m1);
      ps2 += __expf((float)cbuf[s + j] - m2);
    }
  }
  const float rs1 = 1.f / (wred_sum(ps1) + EPS_SM);
  const float rs2 = 1.f / (wred_sum(ps2) + EPS_SM);
  const float bb = 1.f / (1.f + __expf(-ldv(beta, 0, f32)));
  const float ob = 1.f - bb;

  float sp = 0.f;
#pragma unroll
  for (int c = 0; c < 4; ++c) {
    const int j = c * 64 + lane;
    if (c * 64 < deg && j < deg) {
      float tt = (ob * el[c] * rs1 + bb * ec[c] * rs2) * gg[c];
      float p = __expf(tt - 1.f);
      sp += p;
      sg[j] = make_float2(__int_as_float(q[c]), p);  // (src, p)
    }
  }
  for (int c = 4; c * 64 < deg; ++c) {  // overflow: recompute, stash p in lbuf
    const int j = c * 64 + lane;
    if (j < deg) {
      float elx = __expf((float)lbuf[s + j] - m1);
      float ecx = __expf((float)cbuf[s + j] - m2);
      float gx = __int_as_float(csr[s + j].y);
      float px = __expf((ob * elx * rs1 + bb * ecx * rs2) * gx - 1.f);
      lbuf[s + j] = (_Float16)px;
      sp += px;
    }
  }
  const float rinv = 1.f / (wred_sum(sp) + EPS_SM);

  // ---- phase 3 accumulate: LDS (p,src) broadcast, 8 independent gathers ----
  float acc[8] = {0.f, 0.f, 0.f, 0.f, 0.f, 0.f, 0.f, 0.f};
  if (deg <= CAP) {
#pragma unroll 8
    for (int base = 0; base < deg; base += 8) {
      const int j = base + g;
      float2 en = (j < deg) ? sg[j] : make_float2(__int_as_float(wid), 0.f);
      const float pv = en.y;
      const int srcv = __float_as_int(en.x);
      float hv[8];
      unp8(((const uint4*)(Hmat + (size_t)srcv * D))[sub], hv);
#pragma unroll
      for (int i = 0; i < 8; ++i) acc[i] += pv * hv[i];
    }
  } else {
    for (int base = 0; base < deg; base += 8) {
      const int j = base + g;
      float pv;
      int srcv;
      if (j >= deg) {
        pv = 0.f;
        srcv = wid;
      } else if (j < CAP) {
        float2 en = sg[j];
        pv = en.y;
        srcv = __float_as_int(en.x);
      } else {
        pv = (float)lbuf[s + j];
        srcv = csr[s + j].x;
      }
      float hv[8];
      unp8(((const uint4*)(Hmat + (size_t)srcv * D))[sub], hv);
#pragma unroll
      for (int i = 0; i < 8; ++i) acc[i] += pv * hv[i];
    }
  }
#pragma unroll
  for (int i = 0; i < 8; ++i) {
    acc[i] += __shfl_xor(acc[i], 8, 64);
    acc[i] += __shfl_xor(acc[i], 16, 64);
    acc[i] += __shfl_xor(acc[i], 32, 64);
  }
  if (g == 0) {
#pragma unroll
    for (int i = 0; i < 8; ++i) lds_t[wv][8 * sub + i] = acc[i];
  }
  float v = lds_t[wv][lane] * rinv + ldv(bias, lane, f32);
  v = elu1(v);  // elu inside _cosgat
  if (mode == 1) {
    // fused residual MLP: relu(x@rW1+rb1)@rW2+rb2
    float xv = ldv(x, (size_t)wid * D + lane, f32);
    float a1 = ldv(rb1, lane, f32);
    float a2;
    if (f32) {
      const float* w1 = (const float*)rW1;
      const float* w2 = (const float*)rW2;
#pragma unroll 8
      for (int k = 0; k < D; ++k) a1 += __shfl(xv, k, 64) * w1[k * D + lane];
      float tr = fmaxf(a1, 0.f);
      a2 = ((const float*)rb2)[lane];
#pragma unroll 8
      for (int k = 0; k < D; ++k) a2 += __shfl(tr, k, 64) * w2[k * D + lane];
    } else {
      const __hip_bfloat16* w1 = (const __hip_bfloat16*)rW1;
      const __hip_bfloat16* w2 = (const __hip_bfloat16*)rW2;
#pragma unroll 8
      for (int k = 0; k < D; ++k) a1 += __shfl(xv, k, 64) * __bfloat162float(w1[k * D + lane]);
      float tr = fmaxf(a1, 0.f);
      a2 = __bfloat162float(((const __hip_bfloat16*)rb2)[lane]);
#pragma unroll 8
      for (int k = 0; k < D; ++k) a2 += __shfl(tr, k, 64) * __bfloat162float(w2[k * D + lane]);
    }
    stv(out, (size_t)wid * D + lane, f32, sane(v + a2));
  } else {
    v = elu1(v);  // inter-layer elu
    if (mode == 0) {
      prep_node(sane(v), f32, wid, lane, Wn, attn, fh2, Hm2, al2, ar2);
    } else {
      stv(out, (size_t)wid * D + lane, f32, sane(v));
    }
  }
}

extern "C" void kernel_launch(void* const* d_in, const int* in_sizes, int n_in,
                              void* d_out, int out_size, void* d_ws, size_t ws_size,
                              hipStream_t stream) {
  const void* x = d_in[0];
  const int* ei = (const int*)d_in[1];
  const void* w = d_in[2];
  const void* W0 = d_in[3];
  const void* att0 = d_in[4];
  const void* beta0 = d_in[5];
  const void* b0 = d_in[6];
  const void* W1 = d_in[7];
  const void* att1 = d_in[8];
  const void* beta1 = d_in[9];
  const void* b1 = d_in[10];
  const void* rW1 = d_in[11];
  const void* rb1 = d_in[12];
  const void* rW2 = d_in[13];
  const void* rb2 = d_in[14];

  const int N = in_sizes[0] / D;
  const int E = in_sizes[2];

  char* base = (char*)d_ws;
  size_t off = 0;
  auto alloc = [&](size_t bytes) -> void* {
    void* p = base + off;
    off += (bytes + 255) & ~(size_t)255;
    return p;
  };
  // common: ~29.5 MB
  int* flags = (int*)alloc(256);
  int* partials = (int*)alloc(1024 * 4);
  int* counts = (int*)alloc((size_t)N * 4);
  int* wptr = (int*)alloc((size_t)N * 4);
  int* row_ptr = (int*)alloc((size_t)(N + 1) * 4);
  int2* csr = (int2*)alloc((size_t)E * 8);
  _Float16* lbuf = (_Float16*)alloc((size_t)E * 2);
  _Float16* cbuf = (_Float16*)alloc((size_t)E * 2);
  _Float16* fhat = (_Float16*)alloc((size_t)N * D * 2);
  __hip_bfloat16* Hmat = (__hip_bfloat16*)alloc((size_t)N * D * 2);
  float* a_l = (float*)alloc((size_t)N * 4);
  float* a_r = (float*)alloc((size_t)N * 4);
  // fused-path extra: +13.2 MB (second fhat/Hmat/a_l/a_r set)
  _Float16* fhat2 = (_Float16*)alloc((size_t)N * D * 2);
  __hip_bfloat16* Hmat2 = (__hip_bfloat16*)alloc((size_t)N * D * 2);
  float* a_l2 = (float*)alloc((size_t)N * 4);
  float* a_r2 = (float*)alloc((size_t)N * 4);
  const bool fused = (off <= ws_size);

  const int eb2 = (E / 2 + 255) / 256;
  const int nb = (N + 3) / 4;
  const int sb = (N + 255) / 256;

  hipMemsetAsync(counts, 0, (size_t)N * 4, stream);
  // detect + count + layer-0 prep in one kernel
  k_init<<<nb, 256, 0, stream>>>((const unsigned short*)x, ei, flags, counts,
                                 x, W0, att0, fhat, Hmat, a_l, a_r, N, E);
  k_scanA<<<sb, 256, 0, stream>>>(counts, row_ptr, partials, N);
  k_scanB<<<1, 1024, 0, stream>>>(partials, row_ptr, sb, N);
  k_scanC<<<sb, 256, 0, stream>>>(row_ptr, wptr, partials, N);
  k_fill<<<eb2, 256, 0, stream>>>(ei, w, E, N, flags, wptr, csr);

  if (fused) {
    // layer 0 edge + fused layer-1 prep (no h round-trip)
    k_edge<<<nb, 256, 0, stream>>>(row_ptr, csr, lbuf, cbuf, fhat, Hmat, a_l, a_r,
                                   beta0, b0, x, rW1, rb1, rW2, rb2,
                                   W1, att1, fhat2, Hmat2, a_l2, a_r2,
                                   flags, d_out, N, E, 0);
    k_edge<<<nb, 256, 0, stream>>>(row_ptr, csr, lbuf, cbuf, fhat2, Hmat2, a_l2, a_r2,
                                   beta1, b1, x, rW1, rb1, rW2, rb2,
                                   nullptr, nullptr, nullptr, nullptr, nullptr, nullptr,
                                   flags, d_out, N, E, 1);
  } else {
    // fallback: stage h in d_out, separate prep
    k_edge<<<nb, 256, 0, stream>>>(row_ptr, csr, lbuf, cbuf, fhat, Hmat, a_l, a_r,
                                   beta0, b0, x, rW1, rb1, rW2, rb2,
                                   nullptr, nullptr, nullptr, nullptr, nullptr, nullptr,
                                   flags, d_out, N, E, 2);
    k_prep<<<nb, 256, 0, stream>>>(d_out, W1, att1, flags, fhat, Hmat, a_l, a_r, N);
    k_edge<<<nb, 256, 0, stream>>>(row_ptr, csr, lbuf, cbuf, fhat, Hmat, a_l, a_r,
                                   beta1, b1, x, rW1, rb1, rW2, rb2,
                                   nullptr, nullptr, nullptr, nullptr, nullptr, nullptr,
                                   flags, d_out, N, E, 1);
  }
}

// Round 11
// 508.790 us; speedup vs baseline: 1.0492x; 1.0492x over previous
//
#include <hip/hip_runtime.h>
#include <hip/hip_bf16.h>
#include <math.h>

// COSGATEncoder: N=50000, E=1280000, D=64, HEADS=1. f32 in/out (runtime-detected,
// bf16 fallback), edge_index int64 (runtime-detected, int32 fallback).
// R11: R10's LDS (src,p) broadcast idea with CAP=64 (degree is Poisson(25.6),
// max ~50 over 50K nodes) -> 5.1KB LDS/block, occupancy restored; chunk regs
// collapse to scalars. Overflow (deg>64) handled via global bufs (correct, slow).

constexpr int D = 64;
constexpr int CAP = 64;  // LDS-resident edges per node; overflow -> global bufs
constexpr float NEG_SLOPE = 0.2f;
constexpr float EPS_COS = 1e-8f;
constexpr float EPS_SM = 1e-16f;

typedef _Float16 half2_t __attribute__((ext_vector_type(2)));
union U16x8 {
  uint4 u;
  half2_t h[4];
};

__device__ __forceinline__ float wred_sum(float v) {
#pragma unroll
  for (int off = 32; off > 0; off >>= 1) v += __shfl_xor(v, off, 64);
  return v;
}
__device__ __forceinline__ float elu1(float x) { return x > 0.f ? x : __expf(x) - 1.f; }
__device__ __forceinline__ float sane(float v) {
  return (v == v && fabsf(v) < 1e30f) ? v : 0.f;
}
__device__ __forceinline__ float ldv(const void* p, size_t i, int f32) {
  return f32 ? ((const float*)p)[i]
             : __bfloat162float(((const __hip_bfloat16*)p)[i]);
}
__device__ __forceinline__ void stv(void* p, size_t i, int f32, float v) {
  if (f32) ((float*)p)[i] = v;
  else ((__hip_bfloat16*)p)[i] = __float2bfloat16(v);
}
__device__ __forceinline__ float b2f(unsigned short u) {
  return __uint_as_float(((unsigned int)u) << 16);
}
__device__ __forceinline__ void unp8(uint4 u, float* f) {
  f[0] = __uint_as_float(u.x << 16);
  f[1] = __uint_as_float(u.x & 0xffff0000u);
  f[2] = __uint_as_float(u.y << 16);
  f[3] = __uint_as_float(u.y & 0xffff0000u);
  f[4] = __uint_as_float(u.z << 16);
  f[5] = __uint_as_float(u.z & 0xffff0000u);
  f[6] = __uint_as_float(u.w << 16);
  f[7] = __uint_as_float(u.w & 0xffff0000u);
}
__device__ __forceinline__ float dot8(const U16x8& a, const U16x8& b) {
  float d = 0.f;
#if __has_builtin(__builtin_amdgcn_fdot2)
#pragma unroll
  for (int i = 0; i < 4; ++i) d = __builtin_amdgcn_fdot2(a.h[i], b.h[i], d, false);
#else
#pragma unroll
  for (int i = 0; i < 4; ++i) {
    d += (float)a.h[i][0] * (float)b.h[i][0];
    d += (float)a.h[i][1] * (float)b.h[i][1];
  }
#endif
  return d;
}

// shared prep body: node features (lane=feature) -> fhat(f16), Hmat(bf16), a_l, a_r
__device__ __forceinline__ void prep_node(float f, int f32, int wid, int lane,
                                          const void* __restrict__ W,
                                          const void* __restrict__ att,
                                          _Float16* __restrict__ fhat,
                                          __hip_bfloat16* __restrict__ Hmat,
                                          float* __restrict__ a_l,
                                          float* __restrict__ a_r) {
  float n2 = wred_sum(f * f);
  float nrm = fmaxf(sqrtf(n2), EPS_COS);
  fhat[(size_t)wid * D + lane] = (_Float16)(f / nrm);
  float Hc = 0.f;
  if (f32) {
    const float* Wf = (const float*)W;
#pragma unroll 8
    for (int k = 0; k < D; ++k) Hc += __shfl(f, k, 64) * Wf[k * D + lane];
  } else {
    const __hip_bfloat16* Wb = (const __hip_bfloat16*)W;
#pragma unroll 8
    for (int k = 0; k < D; ++k) Hc += __shfl(f, k, 64) * __bfloat162float(Wb[k * D + lane]);
  }
  Hmat[(size_t)wid * D + lane] = __float2bfloat16(Hc);
  float al = wred_sum(Hc * ldv(att, lane, f32));
  float ar = wred_sum(Hc * ldv(att, D + lane, f32));
  if (lane == 0) {
    a_l[wid] = al;
    a_r[wid] = ar;
  }
}

// fused: per-block dtype detect + degree count + layer-0 prep
// (counts zeroed by hipMemsetAsync before this kernel)
__global__ void __launch_bounds__(256) k_init(const unsigned short* __restrict__ xu,
                                              const int* __restrict__ ei,
                                              int* __restrict__ flags,
                                              int* __restrict__ counts,
                                              const void* __restrict__ x,
                                              const void* __restrict__ W,
                                              const void* __restrict__ att,
                                              _Float16* __restrict__ fhat,
                                              __hip_bfloat16* __restrict__ Hmat,
                                              float* __restrict__ a_l,
                                              float* __restrict__ a_r, int N, int E) {
  __shared__ int sf[2];
  const int tid = threadIdx.x;
  if (tid < 64) {
    float v = b2f(xu[tid]);
    float a = fabsf(v);
    unsigned long long m = __ballot(a > 1e-4f && a < 100.f);
    unsigned long long m2 = __ballot(ei[2 * tid + 1] != 0);
    if (tid == 0) {
      sf[0] = (__popcll(m) >= 60) ? 0 : 1;  // 1 => f32
      sf[1] = (m2 == 0ull) ? 1 : 0;         // 1 => int64
      if (blockIdx.x == 0) {
        flags[0] = sf[0];
        flags[1] = sf[1];
      }
    }
  }
  __syncthreads();
  const int f32 = sf[0], wide = sf[1];
  // degree count: 2 edges per thread
  {
    const int e0 = (blockIdx.x * 256 + tid) * 2;
    if (e0 < E) {
      int d0, d1;
      const bool has1 = (e0 + 1 < E);
      if (wide) {
        int4 v = *(const int4*)(ei + 2 * (size_t)E + 2 * (size_t)e0);
        d0 = v.x;
        d1 = v.z;
      } else {
        int2 v = *(const int2*)(ei + (size_t)E + e0);
        d0 = v.x;
        d1 = v.y;
      }
      atomicAdd(&counts[min(max(d0, 0), N - 1)], 1);
      if (has1) atomicAdd(&counts[min(max(d1, 0), N - 1)], 1);
    }
  }
  const int lane = tid & 63;
  const int wid = blockIdx.x * 4 + (tid >> 6);
  if (wid >= N) return;
  float f = ldv(x, (size_t)wid * D + lane, f32);
  prep_node(f, f32, wid, lane, W, att, fhat, Hmat, a_l, a_r);
}

// 3-pass multiblock exclusive scan
__global__ void k_scanA(const int* __restrict__ counts, int* __restrict__ row_ptr,
                        int* __restrict__ partials, int n) {
  __shared__ int sm[256];
  const int t = threadIdx.x;
  const int i = blockIdx.x * 256 + t;
  int v = (i < n) ? counts[i] : 0;
  sm[t] = v;
  __syncthreads();
  for (int off = 1; off < 256; off <<= 1) {
    int u = (t >= off) ? sm[t - off] : 0;
    __syncthreads();
    sm[t] += u;
    __syncthreads();
  }
  if (i < n) row_ptr[i] = sm[t] - v;
  if (t == 255) partials[blockIdx.x] = sm[255];
}
__global__ void __launch_bounds__(1024) k_scanB(int* __restrict__ partials,
                                                int* __restrict__ row_ptr,
                                                int nb, int n) {
  __shared__ int sm[1024];
  const int t = threadIdx.x;
  int v = (t < nb) ? partials[t] : 0;
  sm[t] = v;
  __syncthreads();
  for (int off = 1; off < 1024; off <<= 1) {
    int u = (t >= off) ? sm[t - off] : 0;
    __syncthreads();
    sm[t] += u;
    __syncthreads();
  }
  if (t < nb) partials[t] = sm[t] - v;
  if (t == nb - 1) row_ptr[n] = sm[t];
}
__global__ void k_scanC(int* __restrict__ row_ptr, int* __restrict__ wptr,
                        const int* __restrict__ partials, int n) {
  const int i = blockIdx.x * 256 + threadIdx.x;
  if (i < n) {
    int r = row_ptr[i] + partials[blockIdx.x];
    row_ptr[i] = r;
    wptr[i] = r;
  }
}

// packed entry: .x = src, .y = gate bits (float)
__global__ void k_fill(const int* __restrict__ ei, const void* __restrict__ w,
                       int E, int N, const int* __restrict__ flags,
                       int* __restrict__ wptr, int2* __restrict__ csr) {
  int e0 = (blockIdx.x * blockDim.x + threadIdx.x) * 2;
  if (e0 >= E) return;
  const int wide = flags[1], f32 = flags[0];
  const bool has1 = (e0 + 1 < E);
  int s0, s1, d0, d1;
  if (wide) {
    int4 vs = *(const int4*)(ei + 2 * (size_t)e0);
    int4 vd = *(const int4*)(ei + 2 * (size_t)E + 2 * (size_t)e0);
    s0 = vs.x; s1 = vs.z; d0 = vd.x; d1 = vd.z;
  } else {
    int2 vs = *(const int2*)(ei + e0);
    int2 vd = *(const int2*)(ei + (size_t)E + e0);
    s0 = vs.x; s1 = vs.y; d0 = vd.x; d1 = vd.y;
  }
  float w0, w1 = 0.f;
  if (f32) {
    float2 wv = *(const float2*)((const float*)w + e0);
    w0 = wv.x; w1 = wv.y;
  } else {
    const __hip_bfloat16* wb = (const __hip_bfloat16*)w;
    w0 = __bfloat162float(wb[e0]);
    if (has1) w1 = __bfloat162float(wb[e0 + 1]);
  }
  float g0 = fminf(fmaxf(1.f - 0.25f * fminf(w0, 4.f), 0.f), 1.f);
  int p0 = atomicAdd(&wptr[min(max(d0, 0), N - 1)], 1);
  p0 = min(max(p0, 0), E - 1);
  csr[p0] = make_int2(min(max(s0, 0), N - 1), __float_as_int(g0));
  if (has1) {
    float g1 = fminf(fmaxf(1.f - 0.25f * fminf(w1, 4.f), 0.f), 1.f);
    int p1 = atomicAdd(&wptr[min(max(d1, 0), N - 1)], 1);
    p1 = min(max(p1, 0), E - 1);
    csr[p1] = make_int2(min(max(s1, 0), N - 1), __float_as_int(g1));
  }
}

// standalone prep (fallback path when ws too small for fused buffers)
__global__ void __launch_bounds__(256) k_prep(const void* __restrict__ xin,
                                              const void* __restrict__ W,
                                              const void* __restrict__ att,
                                              const int* __restrict__ flags,
                                              _Float16* __restrict__ fhat,
                                              __hip_bfloat16* __restrict__ Hmat,
                                              float* __restrict__ a_l,
                                              float* __restrict__ a_r, int N) {
  const int lane = threadIdx.x & 63;
  const int wid = (blockIdx.x * 256 + threadIdx.x) >> 6;
  if (wid >= N) return;
  const int f32 = flags[0];
  float f = ldv(xin, (size_t)wid * D + lane, f32);
  prep_node(f, f32, wid, lane, W, att, fhat, Hmat, a_l, a_r);
}

// ---------------- edge kernel: wave per dst node, 8-edge/8-lane groups ----------------
// mode 0: layer 0, fused prep of next layer; mode 1: layer 1, fused residual MLP;
// mode 2: layer 0 fallback (writes h to out)
__global__ void __launch_bounds__(256) k_edge(const int* __restrict__ row_ptr,
                                              const int2* __restrict__ csr,
                                              _Float16* __restrict__ lbuf,
                                              _Float16* __restrict__ cbuf,
                                              const _Float16* __restrict__ fhat,
                                              const __hip_bfloat16* __restrict__ Hmat,
                                              const float* __restrict__ a_l,
                                              const float* __restrict__ a_r,
                                              const void* __restrict__ beta,
                                              const void* __restrict__ bias,
                                              const void* __restrict__ x,
                                              const void* __restrict__ rW1,
                                              const void* __restrict__ rb1,
                                              const void* __restrict__ rW2,
                                              const void* __restrict__ rb2,
                                              const void* __restrict__ Wn,
                                              const void* __restrict__ attn,
                                              _Float16* __restrict__ fh2,
                                              __hip_bfloat16* __restrict__ Hm2,
                                              float* __restrict__ al2,
                                              float* __restrict__ ar2,
                                              const int* __restrict__ flags,
                                              void* __restrict__ out,
                                              int N, int E, int mode) {
  const int lane = threadIdx.x & 63;
  const int wv = threadIdx.x >> 6;
  const int wid = blockIdx.x * 4 + wv;
  __shared__ float2 lds_lc[4][CAP];  // (l, c)
  __shared__ float2 lds_sg[4][CAP];  // (src bits, gate) -> later (src bits, p)
  __shared__ float lds_t[4][D];
  if (wid >= N) return;
  const int f32 = flags[0];
  const int g = lane >> 3;   // edge slot in 8-edge group
  const int sub = lane & 7;  // feature block: [8*sub, 8*sub+8)
  const int s = min(max(row_ptr[wid], 0), E);
  const int e = min(max(row_ptr[wid + 1], s), E);
  const int deg = e - s;
  const float aln = a_l[wid];
  float2* lc = lds_lc[wv];
  float2* sg = lds_sg[wv];

  U16x8 fn;
  fn.u = ((const uint4*)(fhat + (size_t)wid * D))[sub];

  // ---- phase 1: 8 edges/iter (unroll 4), (l,c)->LDS, (src,gate)->LDS ----
  float m1 = -1e30f, m2 = -1e30f;
#pragma unroll 4
  for (int base = 0; base < deg; base += 8) {
    const int j = base + g;
    const bool val = j < deg;
    const int2 en = val ? csr[s + j] : make_int2(wid, 0);
    const int src = en.x;
    U16x8 hv;
    hv.u = ((const uint4*)(fhat + (size_t)src * D))[sub];
    float d = dot8(fn, hv);
    d += __shfl_xor(d, 1, 64);
    d += __shfl_xor(d, 2, 64);
    d += __shfl_xor(d, 4, 64);
    float l = aln + a_r[src];
    l = (l >= 0.f) ? l : NEG_SLOPE * l;
    if (val) {
      m1 = fmaxf(m1, l);
      m2 = fmaxf(m2, d);
      if (sub == 0) {
        if (j < CAP) {
          lc[j] = make_float2(l, d);
          sg[j] = make_float2(__int_as_float(en.x), __int_as_float(en.y));
        } else {
          lbuf[s + j] = (_Float16)l;
          cbuf[s + j] = (_Float16)d;
        }
      }
    }
  }
  m1 = fmaxf(m1, __shfl_xor(m1, 8, 64));
  m1 = fmaxf(m1, __shfl_xor(m1, 16, 64));
  m1 = fmaxf(m1, __shfl_xor(m1, 32, 64));
  m2 = fmaxf(m2, __shfl_xor(m2, 8, 64));
  m2 = fmaxf(m2, __shfl_xor(m2, 16, 64));
  m2 = fmaxf(m2, __shfl_xor(m2, 32, 64));

  // ---- merged phase 2 + 3-prep: chunk 0 via LDS (deg<=64 typical), rest global ----
  float el0 = 0.f, ec0 = 0.f, gg0 = 0.f;
  int q0 = 0;
  float ps1 = 0.f, ps2 = 0.f;
  if (lane < deg) {  // chunk 0: j = lane < 64 = CAP
    float2 en = sg[lane];
    q0 = __float_as_int(en.x);
    gg0 = en.y;  // gate float (bits round-tripped)
    float2 t = lc[lane];
    el0 = __expf(t.x - m1);
    ec0 = __expf(t.y - m2);
    ps1 += el0;
    ps2 += ec0;
  }
  for (int c = 1; c * 64 < deg; ++c) {
    const int j = c * 64 + lane;
    if (j < deg) {
      ps1 += __expf((float)lbuf[s + j] - m1);
      ps2 += __expf((float)cbuf[s + j] - m2);
    }
  }
  const float rs1 = 1.f / (wred_sum(ps1) + EPS_SM);
  const float rs2 = 1.f / (wred_sum(ps2) + EPS_SM);
  const float bb = 1.f / (1.f + __expf(-ldv(beta, 0, f32)));
  const float ob = 1.f - bb;

  float sp = 0.f;
  if (lane < deg) {
    float tt = (ob * el0 * rs1 + bb * ec0 * rs2) * gg0;
    float p0 = __expf(tt - 1.f);
    sp += p0;
    sg[lane] = make_float2(__int_as_float(q0), p0);  // (src, p)
  }
  for (int c = 1; c * 64 < deg; ++c) {  // overflow: recompute, stash p in lbuf
    const int j = c * 64 + lane;
    if (j < deg) {
      float elx = __expf((float)lbuf[s + j] - m1);
      float ecx = __expf((float)cbuf[s + j] - m2);
      float gx = __int_as_float(csr[s + j].y);
      float px = __expf((ob * elx * rs1 + bb * ecx * rs2) * gx - 1.f);
      lbuf[s + j] = (_Float16)px;
      sp += px;
    }
  }
  const float rinv = 1.f / (wred_sum(sp) + EPS_SM);

  // ---- phase 3 accumulate: LDS (src,p) broadcast, independent gathers ----
  float acc[8] = {0.f, 0.f, 0.f, 0.f, 0.f, 0.f, 0.f, 0.f};
  if (deg <= CAP) {
#pragma unroll 4
    for (int base = 0; base < deg; base += 8) {
      const int j = base + g;
      float2 en = (j < deg) ? sg[j] : make_float2(__int_as_float(wid), 0.f);
      const float pv = en.y;
      const int srcv = __float_as_int(en.x);
      float hv[8];
      unp8(((const uint4*)(Hmat + (size_t)srcv * D))[sub], hv);
#pragma unroll
      for (int i = 0; i < 8; ++i) acc[i] += pv * hv[i];
    }
  } else {
    for (int base = 0; base < deg; base += 8) {
      const int j = base + g;
      float pv;
      int srcv;
      if (j >= deg) {
        pv = 0.f;
        srcv = wid;
      } else if (j < CAP) {
        float2 en = sg[j];
        pv = en.y;
        srcv = __float_as_int(en.x);
      } else {
        pv = (float)lbuf[s + j];
        srcv = csr[s + j].x;
      }
      float hv[8];
      unp8(((const uint4*)(Hmat + (size_t)srcv * D))[sub], hv);
#pragma unroll
      for (int i = 0; i < 8; ++i) acc[i] += pv * hv[i];
    }
  }
#pragma unroll
  for (int i = 0; i < 8; ++i) {
    acc[i] += __shfl_xor(acc[i], 8, 64);
    acc[i] += __shfl_xor(acc[i], 16, 64);
    acc[i] += __shfl_xor(acc[i], 32, 64);
  }
  if (g == 0) {
#pragma unroll
    for (int i = 0; i < 8; ++i) lds_t[wv][8 * sub + i] = acc[i];
  }
  float v = lds_t[wv][lane] * rinv + ldv(bias, lane, f32);
  v = elu1(v);  // elu inside _cosgat
  if (mode == 1) {
    // fused residual MLP: relu(x@rW1+rb1)@rW2+rb2
    float xv = ldv(x, (size_t)wid * D + lane, f32);
    float a1 = ldv(rb1, lane, f32);
    float a2;
    if (f32) {
      const float* w1 = (const float*)rW1;
      const float* w2 = (const float*)rW2;
#pragma unroll 8
      for (int k = 0; k < D; ++k) a1 += __shfl(xv, k, 64) * w1[k * D + lane];
      float tr = fmaxf(a1, 0.f);
      a2 = ((const float*)rb2)[lane];
#pragma unroll 8
      for (int k = 0; k < D; ++k) a2 += __shfl(tr, k, 64) * w2[k * D + lane];
    } else {
      const __hip_bfloat16* w1 = (const __hip_bfloat16*)rW1;
      const __hip_bfloat16* w2 = (const __hip_bfloat16*)rW2;
#pragma unroll 8
      for (int k = 0; k < D; ++k) a1 += __shfl(xv, k, 64) * __bfloat162float(w1[k * D + lane]);
      float tr = fmaxf(a1, 0.f);
      a2 = __bfloat162float(((const __hip_bfloat16*)rb2)[lane]);
#pragma unroll 8
      for (int k = 0; k < D; ++k) a2 += __shfl(tr, k, 64) * __bfloat162float(w2[k * D + lane]);
    }
    stv(out, (size_t)wid * D + lane, f32, sane(v + a2));
  } else {
    v = elu1(v);  // inter-layer elu
    if (mode == 0) {
      prep_node(sane(v), f32, wid, lane, Wn, attn, fh2, Hm2, al2, ar2);
    } else {
      stv(out, (size_t)wid * D + lane, f32, sane(v));
    }
  }
}

extern "C" void kernel_launch(void* const* d_in, const int* in_sizes, int n_in,
                              void* d_out, int out_size, void* d_ws, size_t ws_size,
                              hipStream_t stream) {
  const void* x = d_in[0];
  const int* ei = (const int*)d_in[1];
  const void* w = d_in[2];
  const void* W0 = d_in[3];
  const void* att0 = d_in[4];
  const void* beta0 = d_in[5];
  const void* b0 = d_in[6];
  const void* W1 = d_in[7];
  const void* att1 = d_in[8];
  const void* beta1 = d_in[9];
  const void* b1 = d_in[10];
  const void* rW1 = d_in[11];
  const void* rb1 = d_in[12];
  const void* rW2 = d_in[13];
  const void* rb2 = d_in[14];

  const int N = in_sizes[0] / D;
  const int E = in_sizes[2];

  char* base = (char*)d_ws;
  size_t off = 0;
  auto alloc = [&](size_t bytes) -> void* {
    void* p = base + off;
    off += (bytes + 255) & ~(size_t)255;
    return p;
  };
  // common: ~29.5 MB
  int* flags = (int*)alloc(256);
  int* partials = (int*)alloc(1024 * 4);
  int* counts = (int*)alloc((size_t)N * 4);
  int* wptr = (int*)alloc((size_t)N * 4);
  int* row_ptr = (int*)alloc((size_t)(N + 1) * 4);
  int2* csr = (int2*)alloc((size_t)E * 8);
  _Float16* lbuf = (_Float16*)alloc((size_t)E * 2);
  _Float16* cbuf = (_Float16*)alloc((size_t)E * 2);
  _Float16* fhat = (_Float16*)alloc((size_t)N * D * 2);
  __hip_bfloat16* Hmat = (__hip_bfloat16*)alloc((size_t)N * D * 2);
  float* a_l = (float*)alloc((size_t)N * 4);
  float* a_r = (float*)alloc((size_t)N * 4);
  // fused-path extra: +13.2 MB (second fhat/Hmat/a_l/a_r set)
  _Float16* fhat2 = (_Float16*)alloc((size_t)N * D * 2);
  __hip_bfloat16* Hmat2 = (__hip_bfloat16*)alloc((size_t)N * D * 2);
  float* a_l2 = (float*)alloc((size_t)N * 4);
  float* a_r2 = (float*)alloc((size_t)N * 4);
  const bool fused = (off <= ws_size);

  const int eb2 = (E / 2 + 255) / 256;
  const int nb = (N + 3) / 4;
  const int sb = (N + 255) / 256;

  hipMemsetAsync(counts, 0, (size_t)N * 4, stream);
  // detect + count + layer-0 prep in one kernel
  k_init<<<nb, 256, 0, stream>>>((const unsigned short*)x, ei, flags, counts,
                                 x, W0, att0, fhat, Hmat, a_l, a_r, N, E);
  k_scanA<<<sb, 256, 0, stream>>>(counts, row_ptr, partials, N);
  k_scanB<<<1, 1024, 0, stream>>>(partials, row_ptr, sb, N);
  k_scanC<<<sb, 256, 0, stream>>>(row_ptr, wptr, partials, N);
  k_fill<<<eb2, 256, 0, stream>>>(ei, w, E, N, flags, wptr, csr);

  if (fused) {
    // layer 0 edge + fused layer-1 prep (no h round-trip)
    k_edge<<<nb, 256, 0, stream>>>(row_ptr, csr, lbuf, cbuf, fhat, Hmat, a_l, a_r,
                                   beta0, b0, x, rW1, rb1, rW2, rb2,
                                   W1, att1, fhat2, Hmat2, a_l2, a_r2,
                                   flags, d_out, N, E, 0);
    k_edge<<<nb, 256, 0, stream>>>(row_ptr, csr, lbuf, cbuf, fhat2, Hmat2, a_l2, a_r2,
                                   beta1, b1, x, rW1, rb1, rW2, rb2,
                                   nullptr, nullptr, nullptr, nullptr, nullptr, nullptr,
                                   flags, d_out, N, E, 1);
  } else {
    // fallback: stage h in d_out, separate prep
    k_edge<<<nb, 256, 0, stream>>>(row_ptr, csr, lbuf, cbuf, fhat, Hmat, a_l, a_r,
                                   beta0, b0, x, rW1, rb1, rW2, rb2,
                                   nullptr, nullptr, nullptr, nullptr, nullptr, nullptr,
                                   flags, d_out, N, E, 2);
    k_prep<<<nb, 256, 0, stream>>>(d_out, W1, att1, flags, fhat, Hmat, a_l, a_r, N);
    k_edge<<<nb, 256, 0, stream>>>(row_ptr, csr, lbuf, cbuf, fhat, Hmat, a_l, a_r,
                                   beta1, b1, x, rW1, rb1, rW2, rb2,
                                   nullptr, nullptr, nullptr, nullptr, nullptr, nullptr,
                                   flags, d_out, N, E, 1);
  }
}

// Round 12
// 505.623 us; speedup vs baseline: 1.0557x; 1.0063x over previous
//
#include <hip/hip_runtime.h>
#include <hip/hip_bf16.h>
#include <math.h>

// COSGATEncoder: N=50000, E=1280000, D=64, HEADS=1. f32 in/out (runtime-detected,
// bf16 fallback), edge_index int64 (runtime-detected, int32 fallback).
// R12: fhat stored fp8-e4m3 (64B rows; 3.2MB fits per-XCD L2 -> ph1 gathers hit L2),
// csr entry packed to 4B (src:18b | gate:14b). Rest = R11 (CAP=64 LDS (src,p)
// broadcast, fused k_init prep0+count, fused layer-1 prep in layer-0 epilogue).

constexpr int D = 64;
constexpr int CAP = 64;
constexpr float NEG_SLOPE = 0.2f;
constexpr float EPS_COS = 1e-8f;
constexpr float EPS_SM = 1e-16f;

#if defined(__has_builtin)
#if __has_builtin(__builtin_amdgcn_cvt_pk_f32_fp8) && __has_builtin(__builtin_amdgcn_cvt_pk_fp8_f32)
#define HW_FP8 1
#endif
#endif

typedef float floatx2 __attribute__((ext_vector_type(2)));

__device__ __forceinline__ float wred_sum(float v) {
#pragma unroll
  for (int off = 32; off > 0; off >>= 1) v += __shfl_xor(v, off, 64);
  return v;
}
__device__ __forceinline__ float elu1(float x) { return x > 0.f ? x : __expf(x) - 1.f; }
__device__ __forceinline__ float sane(float v) {
  return (v == v && fabsf(v) < 1e30f) ? v : 0.f;
}
__device__ __forceinline__ float ldv(const void* p, size_t i, int f32) {
  return f32 ? ((const float*)p)[i]
             : __bfloat162float(((const __hip_bfloat16*)p)[i]);
}
__device__ __forceinline__ void stv(void* p, size_t i, int f32, float v) {
  if (f32) ((float*)p)[i] = v;
  else ((__hip_bfloat16*)p)[i] = __float2bfloat16(v);
}
__device__ __forceinline__ float b2f(unsigned short u) {
  return __uint_as_float(((unsigned int)u) << 16);
}
__device__ __forceinline__ void unp8(uint4 u, float* f) {
  f[0] = __uint_as_float(u.x << 16);
  f[1] = __uint_as_float(u.x & 0xffff0000u);
  f[2] = __uint_as_float(u.y << 16);
  f[3] = __uint_as_float(u.y & 0xffff0000u);
  f[4] = __uint_as_float(u.z << 16);
  f[5] = __uint_as_float(u.z & 0xffff0000u);
  f[6] = __uint_as_float(u.w << 16);
  f[7] = __uint_as_float(u.w & 0xffff0000u);
}

// ---- fp8 helpers: HW e4m3 when available, f16-msb (e5m2-like) fallback ----
__device__ __forceinline__ unsigned char enc_fp8(float v) {
#ifdef HW_FP8
  int pk = __builtin_amdgcn_cvt_pk_fp8_f32(v, v, 0, false);
  return (unsigned char)(pk & 0xFF);
#else
  _Float16 h = (_Float16)v;
  unsigned short ub;
  __builtin_memcpy(&ub, &h, 2);
  return (unsigned char)((ub + 0x80) >> 8);  // RNE-ish truncate to top byte
#endif
}
__device__ __forceinline__ void dec_fp8x8(uint2 u, float* f) {
#ifdef HW_FP8
  floatx2 a = __builtin_amdgcn_cvt_pk_f32_fp8(u.x, false);
  floatx2 b = __builtin_amdgcn_cvt_pk_f32_fp8(u.x, true);
  floatx2 c = __builtin_amdgcn_cvt_pk_f32_fp8(u.y, false);
  floatx2 d = __builtin_amdgcn_cvt_pk_f32_fp8(u.y, true);
  f[0] = a[0]; f[1] = a[1]; f[2] = b[0]; f[3] = b[1];
  f[4] = c[0]; f[5] = c[1]; f[6] = d[0]; f[7] = d[1];
#else
#pragma unroll
  for (int i = 0; i < 8; ++i) {
    unsigned int byte = (i < 4 ? (u.x >> (8 * i)) : (u.y >> (8 * (i - 4)))) & 0xFF;
    unsigned short hb = (unsigned short)(byte << 8);
    _Float16 h;
    __builtin_memcpy(&h, &hb, 2);
    f[i] = (float)h;
  }
#endif
}

// packed csr entry: bits 0..17 = src, bits 18..31 = gate quantized to 14 bits
__device__ __forceinline__ unsigned int pack_sg(int src, float g) {
  int gq = (int)(g * 16383.f + 0.5f);
  return ((unsigned int)src & 0x3FFFFu) | ((unsigned int)gq << 18);
}
__device__ __forceinline__ int upk_src(unsigned int e, int N) {
  return min((int)(e & 0x3FFFFu), N - 1);
}
__device__ __forceinline__ float upk_gate(unsigned int e) {
  return (float)(e >> 18) * (1.f / 16383.f);
}

// shared prep body: node features (lane=feature) -> fhat(fp8), Hmat(bf16), a_l, a_r
__device__ __forceinline__ void prep_node(float f, int f32, int wid, int lane,
                                          const void* __restrict__ W,
                                          const void* __restrict__ att,
                                          unsigned char* __restrict__ fhat,
                                          __hip_bfloat16* __restrict__ Hmat,
                                          float* __restrict__ a_l,
                                          float* __restrict__ a_r) {
  float n2 = wred_sum(f * f);
  float nrm = fmaxf(sqrtf(n2), EPS_COS);
  fhat[(size_t)wid * D + lane] = enc_fp8(f / nrm);
  float Hc = 0.f;
  if (f32) {
    const float* Wf = (const float*)W;
#pragma unroll 8
    for (int k = 0; k < D; ++k) Hc += __shfl(f, k, 64) * Wf[k * D + lane];
  } else {
    const __hip_bfloat16* Wb = (const __hip_bfloat16*)W;
#pragma unroll 8
    for (int k = 0; k < D; ++k) Hc += __shfl(f, k, 64) * __bfloat162float(Wb[k * D + lane]);
  }
  Hmat[(size_t)wid * D + lane] = __float2bfloat16(Hc);
  float al = wred_sum(Hc * ldv(att, lane, f32));
  float ar = wred_sum(Hc * ldv(att, D + lane, f32));
  if (lane == 0) {
    a_l[wid] = al;
    a_r[wid] = ar;
  }
}

// fused: per-block dtype detect + degree count + layer-0 prep
__global__ void __launch_bounds__(256) k_init(const unsigned short* __restrict__ xu,
                                              const int* __restrict__ ei,
                                              int* __restrict__ flags,
                                              int* __restrict__ counts,
                                              const void* __restrict__ x,
                                              const void* __restrict__ W,
                                              const void* __restrict__ att,
                                              unsigned char* __restrict__ fhat,
                                              __hip_bfloat16* __restrict__ Hmat,
                                              float* __restrict__ a_l,
                                              float* __restrict__ a_r, int N, int E) {
  __shared__ int sf[2];
  const int tid = threadIdx.x;
  if (tid < 64) {
    float v = b2f(xu[tid]);
    float a = fabsf(v);
    unsigned long long m = __ballot(a > 1e-4f && a < 100.f);
    unsigned long long m2 = __ballot(ei[2 * tid + 1] != 0);
    if (tid == 0) {
      sf[0] = (__popcll(m) >= 60) ? 0 : 1;  // 1 => f32
      sf[1] = (m2 == 0ull) ? 1 : 0;         // 1 => int64
      if (blockIdx.x == 0) {
        flags[0] = sf[0];
        flags[1] = sf[1];
      }
    }
  }
  __syncthreads();
  const int f32 = sf[0], wide = sf[1];
  {
    const int e0 = (blockIdx.x * 256 + tid) * 2;
    if (e0 < E) {
      int d0, d1;
      const bool has1 = (e0 + 1 < E);
      if (wide) {
        int4 v = *(const int4*)(ei + 2 * (size_t)E + 2 * (size_t)e0);
        d0 = v.x;
        d1 = v.z;
      } else {
        int2 v = *(const int2*)(ei + (size_t)E + e0);
        d0 = v.x;
        d1 = v.y;
      }
      atomicAdd(&counts[min(max(d0, 0), N - 1)], 1);
      if (has1) atomicAdd(&counts[min(max(d1, 0), N - 1)], 1);
    }
  }
  const int lane = tid & 63;
  const int wid = blockIdx.x * 4 + (tid >> 6);
  if (wid >= N) return;
  float f = ldv(x, (size_t)wid * D + lane, f32);
  prep_node(f, f32, wid, lane, W, att, fhat, Hmat, a_l, a_r);
}

// 3-pass multiblock exclusive scan
__global__ void k_scanA(const int* __restrict__ counts, int* __restrict__ row_ptr,
                        int* __restrict__ partials, int n) {
  __shared__ int sm[256];
  const int t = threadIdx.x;
  const int i = blockIdx.x * 256 + t;
  int v = (i < n) ? counts[i] : 0;
  sm[t] = v;
  __syncthreads();
  for (int off = 1; off < 256; off <<= 1) {
    int u = (t >= off) ? sm[t - off] : 0;
    __syncthreads();
    sm[t] += u;
    __syncthreads();
  }
  if (i < n) row_ptr[i] = sm[t] - v;
  if (t == 255) partials[blockIdx.x] = sm[255];
}
__global__ void __launch_bounds__(1024) k_scanB(int* __restrict__ partials,
                                                int* __restrict__ row_ptr,
                                                int nb, int n) {
  __shared__ int sm[1024];
  const int t = threadIdx.x;
  int v = (t < nb) ? partials[t] : 0;
  sm[t] = v;
  __syncthreads();
  for (int off = 1; off < 1024; off <<= 1) {
    int u = (t >= off) ? sm[t - off] : 0;
    __syncthreads();
    sm[t] += u;
    __syncthreads();
  }
  if (t < nb) partials[t] = sm[t] - v;
  if (t == nb - 1) row_ptr[n] = sm[t];
}
__global__ void k_scanC(int* __restrict__ row_ptr, int* __restrict__ wptr,
                        const int* __restrict__ partials, int n) {
  const int i = blockIdx.x * 256 + threadIdx.x;
  if (i < n) {
    int r = row_ptr[i] + partials[blockIdx.x];
    row_ptr[i] = r;
    wptr[i] = r;
  }
}

__global__ void k_fill(const int* __restrict__ ei, const void* __restrict__ w,
                       int E, int N, const int* __restrict__ flags,
                       int* __restrict__ wptr, unsigned int* __restrict__ csr) {
  int e0 = (blockIdx.x * blockDim.x + threadIdx.x) * 2;
  if (e0 >= E) return;
  const int wide = flags[1], f32 = flags[0];
  const bool has1 = (e0 + 1 < E);
  int s0, s1, d0, d1;
  if (wide) {
    int4 vs = *(const int4*)(ei + 2 * (size_t)e0);
    int4 vd = *(const int4*)(ei + 2 * (size_t)E + 2 * (size_t)e0);
    s0 = vs.x; s1 = vs.z; d0 = vd.x; d1 = vd.z;
  } else {
    int2 vs = *(const int2*)(ei + e0);
    int2 vd = *(const int2*)(ei + (size_t)E + e0);
    s0 = vs.x; s1 = vs.y; d0 = vd.x; d1 = vd.y;
  }
  float w0, w1 = 0.f;
  if (f32) {
    float2 wv = *(const float2*)((const float*)w + e0);
    w0 = wv.x; w1 = wv.y;
  } else {
    const __hip_bfloat16* wb = (const __hip_bfloat16*)w;
    w0 = __bfloat162float(wb[e0]);
    if (has1) w1 = __bfloat162float(wb[e0 + 1]);
  }
  float g0 = fminf(fmaxf(1.f - 0.25f * fminf(w0, 4.f), 0.f), 1.f);
  int p0 = atomicAdd(&wptr[min(max(d0, 0), N - 1)], 1);
  p0 = min(max(p0, 0), E - 1);
  csr[p0] = pack_sg(min(max(s0, 0), N - 1), g0);
  if (has1) {
    float g1 = fminf(fmaxf(1.f - 0.25f * fminf(w1, 4.f), 0.f), 1.f);
    int p1 = atomicAdd(&wptr[min(max(d1, 0), N - 1)], 1);
    p1 = min(max(p1, 0), E - 1);
    csr[p1] = pack_sg(min(max(s1, 0), N - 1), g1);
  }
}

// standalone prep (fallback path)
__global__ void __launch_bounds__(256) k_prep(const void* __restrict__ xin,
                                              const void* __restrict__ W,
                                              const void* __restrict__ att,
                                              const int* __restrict__ flags,
                                              unsigned char* __restrict__ fhat,
                                              __hip_bfloat16* __restrict__ Hmat,
                                              float* __restrict__ a_l,
                                              float* __restrict__ a_r, int N) {
  const int lane = threadIdx.x & 63;
  const int wid = (blockIdx.x * 256 + threadIdx.x) >> 6;
  if (wid >= N) return;
  const int f32 = flags[0];
  float f = ldv(xin, (size_t)wid * D + lane, f32);
  prep_node(f, f32, wid, lane, W, att, fhat, Hmat, a_l, a_r);
}

// ---------------- edge kernel: wave per dst node, 8-edge/8-lane groups ----------------
__global__ void __launch_bounds__(256) k_edge(const int* __restrict__ row_ptr,
                                              const unsigned int* __restrict__ csr,
                                              _Float16* __restrict__ lbuf,
                                              _Float16* __restrict__ cbuf,
                                              const unsigned char* __restrict__ fhat,
                                              const __hip_bfloat16* __restrict__ Hmat,
                                              const float* __restrict__ a_l,
                                              const float* __restrict__ a_r,
                                              const void* __restrict__ beta,
                                              const void* __restrict__ bias,
                                              const void* __restrict__ x,
                                              const void* __restrict__ rW1,
                                              const void* __restrict__ rb1,
                                              const void* __restrict__ rW2,
                                              const void* __restrict__ rb2,
                                              const void* __restrict__ Wn,
                                              const void* __restrict__ attn,
                                              unsigned char* __restrict__ fh2,
                                              __hip_bfloat16* __restrict__ Hm2,
                                              float* __restrict__ al2,
                                              float* __restrict__ ar2,
                                              const int* __restrict__ flags,
                                              void* __restrict__ out,
                                              int N, int E, int mode) {
  const int lane = threadIdx.x & 63;
  const int wv = threadIdx.x >> 6;
  const int wid = blockIdx.x * 4 + wv;
  __shared__ float2 lds_lc[4][CAP];  // (l, c)
  __shared__ float2 lds_sg[4][CAP];  // (packed bits, -) -> later (src bits, p)
  __shared__ float lds_t[4][D];
  if (wid >= N) return;
  const int f32 = flags[0];
  const int g = lane >> 3;   // edge slot in 8-edge group
  const int sub = lane & 7;  // feature block: [8*sub, 8*sub+8)
  const int s = min(max(row_ptr[wid], 0), E);
  const int e = min(max(row_ptr[wid + 1], s), E);
  const int deg = e - s;
  const float aln = a_l[wid];
  float2* lc = lds_lc[wv];
  float2* sg = lds_sg[wv];

  float fn[8];
  dec_fp8x8(((const uint2*)(fhat + (size_t)wid * D))[sub], fn);

  // ---- phase 1: 8 edges/iter (unroll 4); fp8 64B row gathers ----
  float m1 = -1e30f, m2 = -1e30f;
#pragma unroll 4
  for (int base = 0; base < deg; base += 8) {
    const int j = base + g;
    const bool val = j < deg;
    const unsigned int en = val ? csr[s + j] : (unsigned int)wid;
    const int src = upk_src(en, N);
    float hv[8];
    dec_fp8x8(((const uint2*)(fhat + (size_t)src * D))[sub], hv);
    float d = 0.f;
#pragma unroll
    for (int i = 0; i < 8; ++i) d += fn[i] * hv[i];
    d += __shfl_xor(d, 1, 64);
    d += __shfl_xor(d, 2, 64);
    d += __shfl_xor(d, 4, 64);
    float l = aln + a_r[src];
    l = (l >= 0.f) ? l : NEG_SLOPE * l;
    if (val) {
      m1 = fmaxf(m1, l);
      m2 = fmaxf(m2, d);
      if (sub == 0) {
        if (j < CAP) {
          lc[j] = make_float2(l, d);
          sg[j] = make_float2(__uint_as_float(en), 0.f);
        } else {
          lbuf[s + j] = (_Float16)l;
          cbuf[s + j] = (_Float16)d;
        }
      }
    }
  }
  m1 = fmaxf(m1, __shfl_xor(m1, 8, 64));
  m1 = fmaxf(m1, __shfl_xor(m1, 16, 64));
  m1 = fmaxf(m1, __shfl_xor(m1, 32, 64));
  m2 = fmaxf(m2, __shfl_xor(m2, 8, 64));
  m2 = fmaxf(m2, __shfl_xor(m2, 16, 64));
  m2 = fmaxf(m2, __shfl_xor(m2, 32, 64));

  // ---- merged phase 2 + 3-prep: chunk 0 via LDS (deg<=64 typical), rest global ----
  float el0 = 0.f, ec0 = 0.f, gg0 = 0.f;
  int q0 = 0;
  float ps1 = 0.f, ps2 = 0.f;
  if (lane < deg) {
    unsigned int en = __float_as_uint(sg[lane].x);
    q0 = upk_src(en, N);
    gg0 = upk_gate(en);
    float2 t = lc[lane];
    el0 = __expf(t.x - m1);
    ec0 = __expf(t.y - m2);
    ps1 += el0;
    ps2 += ec0;
  }
  for (int c = 1; c * 64 < deg; ++c) {
    const int j = c * 64 + lane;
    if (j < deg) {
      ps1 += __expf((float)lbuf[s + j] - m1);
      ps2 += __expf((float)cbuf[s + j] - m2);
    }
  }
  const float rs1 = 1.f / (wred_sum(ps1) + EPS_SM);
  const float rs2 = 1.f / (wred_sum(ps2) + EPS_SM);
  const float bb = 1.f / (1.f + __expf(-ldv(beta, 0, f32)));
  const float ob = 1.f - bb;

  float sp = 0.f;
  if (lane < deg) {
    float tt = (ob * el0 * rs1 + bb * ec0 * rs2) * gg0;
    float p0 = __expf(tt - 1.f);
    sp += p0;
    sg[lane] = make_float2(__int_as_float(q0), p0);  // (src, p)
  }
  for (int c = 1; c * 64 < deg; ++c) {  // overflow: recompute, stash p in lbuf
    const int j = c * 64 + lane;
    if (j < deg) {
      float elx = __expf((float)lbuf[s + j] - m1);
      float ecx = __expf((float)cbuf[s + j] - m2);
      float gx = upk_gate(csr[s + j]);
      float px = __expf((ob * elx * rs1 + bb * ecx * rs2) * gx - 1.f);
      lbuf[s + j] = (_Float16)px;
      sp += px;
    }
  }
  const float rinv = 1.f / (wred_sum(sp) + EPS_SM);

  // ---- phase 3 accumulate: LDS (src,p) broadcast, independent gathers ----
  float acc[8] = {0.f, 0.f, 0.f, 0.f, 0.f, 0.f, 0.f, 0.f};
  if (deg <= CAP) {
#pragma unroll 4
    for (int base = 0; base < deg; base += 8) {
      const int j = base + g;
      float2 en = (j < deg) ? sg[j] : make_float2(__int_as_float(wid), 0.f);
      const float pv = en.y;
      const int srcv = __float_as_int(en.x);
      float hv[8];
      unp8(((const uint4*)(Hmat + (size_t)srcv * D))[sub], hv);
#pragma unroll
      for (int i = 0; i < 8; ++i) acc[i] += pv * hv[i];
    }
  } else {
    for (int base = 0; base < deg; base += 8) {
      const int j = base + g;
      float pv;
      int srcv;
      if (j >= deg) {
        pv = 0.f;
        srcv = wid;
      } else if (j < CAP) {
        float2 en = sg[j];
        pv = en.y;
        srcv = __float_as_int(en.x);
      } else {
        pv = (float)lbuf[s + j];
        srcv = upk_src(csr[s + j], N);
      }
      float hv[8];
      unp8(((const uint4*)(Hmat + (size_t)srcv * D))[sub], hv);
#pragma unroll
      for (int i = 0; i < 8; ++i) acc[i] += pv * hv[i];
    }
  }
#pragma unroll
  for (int i = 0; i < 8; ++i) {
    acc[i] += __shfl_xor(acc[i], 8, 64);
    acc[i] += __shfl_xor(acc[i], 16, 64);
    acc[i] += __shfl_xor(acc[i], 32, 64);
  }
  if (g == 0) {
#pragma unroll
    for (int i = 0; i < 8; ++i) lds_t[wv][8 * sub + i] = acc[i];
  }
  float v = lds_t[wv][lane] * rinv + ldv(bias, lane, f32);
  v = elu1(v);  // elu inside _cosgat
  if (mode == 1) {
    // fused residual MLP: relu(x@rW1+rb1)@rW2+rb2
    float xv = ldv(x, (size_t)wid * D + lane, f32);
    float a1 = ldv(rb1, lane, f32);
    float a2;
    if (f32) {
      const float* w1 = (const float*)rW1;
      const float* w2 = (const float*)rW2;
#pragma unroll 8
      for (int k = 0; k < D; ++k) a1 += __shfl(xv, k, 64) * w1[k * D + lane];
      float tr = fmaxf(a1, 0.f);
      a2 = ((const float*)rb2)[lane];
#pragma unroll 8
      for (int k = 0; k < D; ++k) a2 += __shfl(tr, k, 64) * w2[k * D + lane];
    } else {
      const __hip_bfloat16* w1 = (const __hip_bfloat16*)rW1;
      const __hip_bfloat16* w2 = (const __hip_bfloat16*)rW2;
#pragma unroll 8
      for (int k = 0; k < D; ++k) a1 += __shfl(xv, k, 64) * __bfloat162float(w1[k * D + lane]);
      float tr = fmaxf(a1, 0.f);
      a2 = __bfloat162float(((const __hip_bfloat16*)rb2)[lane]);
#pragma unroll 8
      for (int k = 0; k < D; ++k) a2 += __shfl(tr, k, 64) * __bfloat162float(w2[k * D + lane]);
    }
    stv(out, (size_t)wid * D + lane, f32, sane(v + a2));
  } else {
    v = elu1(v);  // inter-layer elu
    if (mode == 0) {
      prep_node(sane(v), f32, wid, lane, Wn, attn, fh2, Hm2, al2, ar2);
    } else {
      stv(out, (size_t)wid * D + lane, f32, sane(v));
    }
  }
}

extern "C" void kernel_launch(void* const* d_in, const int* in_sizes, int n_in,
                              void* d_out, int out_size, void* d_ws, size_t ws_size,
                              hipStream_t stream) {
  const void* x = d_in[0];
  const int* ei = (const int*)d_in[1];
  const void* w = d_in[2];
  const void* W0 = d_in[3];
  const void* att0 = d_in[4];
  const void* beta0 = d_in[5];
  const void* b0 = d_in[6];
  const void* W1 = d_in[7];
  const void* att1 = d_in[8];
  const void* beta1 = d_in[9];
  const void* b1 = d_in[10];
  const void* rW1 = d_in[11];
  const void* rb1 = d_in[12];
  const void* rW2 = d_in[13];
  const void* rb2 = d_in[14];

  const int N = in_sizes[0] / D;
  const int E = in_sizes[2];

  char* base = (char*)d_ws;
  size_t off = 0;
  auto alloc = [&](size_t bytes) -> void* {
    void* p = base + off;
    off += (bytes + 255) & ~(size_t)255;
    return p;
  };
  int* flags = (int*)alloc(256);
  int* partials = (int*)alloc(1024 * 4);
  int* counts = (int*)alloc((size_t)N * 4);
  int* wptr = (int*)alloc((size_t)N * 4);
  int* row_ptr = (int*)alloc((size_t)(N + 1) * 4);
  unsigned int* csr = (unsigned int*)alloc((size_t)E * 4);
  _Float16* lbuf = (_Float16*)alloc((size_t)E * 2);
  _Float16* cbuf = (_Float16*)alloc((size_t)E * 2);
  unsigned char* fhat = (unsigned char*)alloc((size_t)N * D);
  __hip_bfloat16* Hmat = (__hip_bfloat16*)alloc((size_t)N * D * 2);
  float* a_l = (float*)alloc((size_t)N * 4);
  float* a_r = (float*)alloc((size_t)N * 4);
  unsigned char* fhat2 = (unsigned char*)alloc((size_t)N * D);
  __hip_bfloat16* Hmat2 = (__hip_bfloat16*)alloc((size_t)N * D * 2);
  float* a_l2 = (float*)alloc((size_t)N * 4);
  float* a_r2 = (float*)alloc((size_t)N * 4);
  const bool fused = (off <= ws_size);

  const int eb2 = (E / 2 + 255) / 256;
  const int nb = (N + 3) / 4;
  const int sb = (N + 255) / 256;

  hipMemsetAsync(counts, 0, (size_t)N * 4, stream);
  k_init<<<nb, 256, 0, stream>>>((const unsigned short*)x, ei, flags, counts,
                                 x, W0, att0, fhat, Hmat, a_l, a_r, N, E);
  k_scanA<<<sb, 256, 0, stream>>>(counts, row_ptr, partials, N);
  k_scanB<<<1, 1024, 0, stream>>>(partials, row_ptr, sb, N);
  k_scanC<<<sb, 256, 0, stream>>>(row_ptr, wptr, partials, N);
  k_fill<<<eb2, 256, 0, stream>>>(ei, w, E, N, flags, wptr, csr);

  if (fused) {
    k_edge<<<nb, 256, 0, stream>>>(row_ptr, csr, lbuf, cbuf, fhat, Hmat, a_l, a_r,
                                   beta0, b0, x, rW1, rb1, rW2, rb2,
                                   W1, att1, fhat2, Hmat2, a_l2, a_r2,
                                   flags, d_out, N, E, 0);
    k_edge<<<nb, 256, 0, stream>>>(row_ptr, csr, lbuf, cbuf, fhat2, Hmat2, a_l2, a_r2,
                                   beta1, b1, x, rW1, rb1, rW2, rb2,
                                   nullptr, nullptr, nullptr, nullptr, nullptr, nullptr,
                                   flags, d_out, N, E, 1);
  } else {
    k_edge<<<nb, 256, 0, stream>>>(row_ptr, csr, lbuf, cbuf, fhat, Hmat, a_l, a_r,
                                   beta0, b0, x, rW1, rb1, rW2, rb2,
                                   nullptr, nullptr, nullptr, nullptr, nullptr, nullptr,
                                   flags, d_out, N, E, 2);
    k_prep<<<nb, 256, 0, stream>>>(d_out, W1, att1, flags, fhat, Hmat, a_l, a_r, N);
    k_edge<<<nb, 256, 0, stream>>>(row_ptr, csr, lbuf, cbuf, fhat, Hmat, a_l, a_r,
                                   beta1, b1, x, rW1, rb1, rW2, rb2,
                                   nullptr, nullptr, nullptr, nullptr, nullptr, nullptr,
                                   flags, d_out, N, E, 1);
  }
}